// Round 6
// baseline (253.121 us; speedup 1.0000x reference)
//
#include <hip/hip_runtime.h>
#include <cstdint>
#include <cstddef>

#define B_ 4
#define T_ 2048
#define C_ 1024
#define M_ (B_ * T_)   // 8192 rows
#define HALF_ 8
#define W_ 17
#define NT 32          // K-tiles of BK=32 (K=1024 both GEMMs)

typedef unsigned short u16;
typedef _Float16 half8 __attribute__((ext_vector_type(8)));
typedef float f32x16 __attribute__((ext_vector_type(16)));
typedef unsigned short ushort8v __attribute__((ext_vector_type(8)));

__device__ __forceinline__ ushort4 cvt4(float4 v) {
    ushort4 o;
    _Float16 a = (_Float16)v.x; o.x = __builtin_bit_cast(unsigned short, a);
    _Float16 b = (_Float16)v.y; o.y = __builtin_bit_cast(unsigned short, b);
    _Float16 c = (_Float16)v.z; o.z = __builtin_bit_cast(unsigned short, c);
    _Float16 d = (_Float16)v.w; o.w = __builtin_bit_cast(unsigned short, d);
    return o;
}

// ================= fragment-major layouts =================
// A/B-frag (32-row granularity): element [row][ch] lives at
//   ((row>>5)*64 + (ch>>4))*512 + ((row&31) + 32*((ch>>3)&1))*8 + (ch&7)
// For mfma_32x32x16_f16: A-operand lane l = [row=l&31][ch=(l>>5)*8+e];
// B-operand lane l = [ch-k=(l>>5)*8+e][col=l&31]. Same storage serves both.
// V-frag (16-token k-slice granularity for PV): element [tok][ch] at
//   ((tok>>4)*32 + (ch>>5))*512 + ((ch&31) + 32*((tok>>3)&1))*8 + (tok&7)
// -> B-operand for PV: lane l = [tok-k=(l>>5)*8+e][col ch=l&31].

// ---------------- prologue: coalesced LDS-transpose to frag-major --------
__global__ void prologue2(const float* __restrict__ x,
                          const float* __restrict__ Wq, const float* __restrict__ Wk,
                          const float* __restrict__ Wv, const float* __restrict__ Wo,
                          const float* __restrict__ bq, const float* __restrict__ bk,
                          const float* __restrict__ bv,
                          u16* __restrict__ xf, u16* __restrict__ wfq,
                          u16* __restrict__ wfo, float* __restrict__ bcat) {
    const int blk = blockIdx.x;
    const int tid = threadIdx.x;
    if (blk >= 3072) {
        int i = (blk - 3072) * 256 + tid;
        const float* src = (i < 1024) ? bq : (i < 2048) ? bk : bv;
        bcat[i] = src[i & 1023];
        return;
    }
    __shared__ ushort8v g16[512];   // 32 rows x 16 granules(16B), XOR-swizzled
    const float* src;
    u16* dst;
    size_t chunk_base;
    int kg;
    if (blk < 2048) {
        const int mt = blk >> 3; kg = blk & 7;
        src = x + (size_t)mt * 32 * C_;
        dst = xf; chunk_base = (size_t)mt * 64;
    } else {
        const int w = blk - 2048;
        const int mat = w >> 8, nt = (w >> 3) & 31; kg = w & 7;
        src = ((mat == 0) ? Wq : (mat == 1) ? Wk : (mat == 2) ? Wv : Wo)
              + (size_t)nt * 32 * C_;
        if (mat < 3) { dst = wfq; chunk_base = (size_t)(mat * 32 + nt) * 64; }
        else         { dst = wfo; chunk_base = (size_t)nt * 64; }
    }
    const int r = tid >> 3, gc = (tid & 7) * 2;
    const float4* s4 = (const float4*)(src + (size_t)r * C_ + kg * 128 + (tid & 7) * 16);
    float4 f0 = s4[0], f1 = s4[1], f2 = s4[2], f3 = s4[3];
    ushort4 h0 = cvt4(f0), h1 = cvt4(f1), h2 = cvt4(f2), h3 = cvt4(f3);
    ushort8v ga, gb;
    ga[0]=h0.x; ga[1]=h0.y; ga[2]=h0.z; ga[3]=h0.w;
    ga[4]=h1.x; ga[5]=h1.y; ga[6]=h1.z; ga[7]=h1.w;
    gb[0]=h2.x; gb[1]=h2.y; gb[2]=h2.z; gb[3]=h2.w;
    gb[4]=h3.x; gb[5]=h3.y; gb[6]=h3.z; gb[7]=h3.w;
    g16[r * 16 + ((gc    ) ^ (r & 15))] = ga;
    g16[r * 16 + ((gc + 1) ^ (r & 15))] = gb;
    __syncthreads();
    const int lane = tid & 63, rr = lane & 31, hi = lane >> 5;
#pragma unroll
    for (int r2 = 0; r2 < 2; ++r2) {
        const int ksl = r2 * 4 + (tid >> 6);
        const int g = ksl * 2 + hi;
        ushort8v v = g16[rr * 16 + (g ^ (rr & 15))];
        *(ushort8v*)(dst + ((chunk_base + kg * 8 + ksl) * 64 + lane) * 8) = v;
    }
}

// ---------------- LDS-staged pipelined QKV GEMM ----------------
// BM=256 x BN=128 x BK=32; 4 waves (2M x 2N), wave = 128x64. 3 LDS buffers
// x 24KB = 72KB -> 2 blocks/CU; depth-2 staging, counted vmcnt(6). Epilogue
// writes Q,K in A/B-frag-major and V in V-frag (attn_mfma operand layouts).

#define AS1_ __attribute__((address_space(1)))
#define AS3_ __attribute__((address_space(3)))

__device__ __forceinline__ void gload16(const u16* g, u16* l) {
    __builtin_amdgcn_global_load_lds((AS1_ void*)g, (AS3_ void*)l, 16, 0, 0);
}

#define MFMA_ __builtin_amdgcn_mfma_f32_32x32x16_f16

#define STAGE(NB, KT) { const size_t ko = (size_t)(KT) * 1024;            \
    gload16(gA0 + ko, (NB) + lA0); gload16(gA1 + ko, (NB) + lA1);         \
    gload16(gA2 + ko, (NB) + lA2); gload16(gA3 + ko, (NB) + lA3);         \
    gload16(gB0 + ko, (NB) + lB0); gload16(gB1 + ko, (NB) + lB1); }

#define TILE(CB, NB, KT, DOSTG, VW)                                        \
  {                                                                        \
    half8 a0 = *(const half8*)((CB) + oA);                                 \
    half8 a1 = *(const half8*)((CB) + oA + 1024);                          \
    half8 a2 = *(const half8*)((CB) + oA + 2048);                          \
    half8 a3 = *(const half8*)((CB) + oA + 3072);                          \
    half8 b0v = *(const half8*)((CB) + oB);                                \
    half8 b1v = *(const half8*)((CB) + oB + 1024);                         \
    if (DOSTG) STAGE(NB, (KT) + 2);                                        \
    __builtin_amdgcn_s_setprio(1);                                         \
    acc00 = MFMA_(a0, b0v, acc00, 0, 0, 0);                                \
    acc01 = MFMA_(a0, b1v, acc01, 0, 0, 0);                                \
    acc10 = MFMA_(a1, b0v, acc10, 0, 0, 0);                                \
    acc11 = MFMA_(a1, b1v, acc11, 0, 0, 0);                                \
    acc20 = MFMA_(a2, b0v, acc20, 0, 0, 0);                                \
    acc21 = MFMA_(a2, b1v, acc21, 0, 0, 0);                                \
    acc30 = MFMA_(a3, b0v, acc30, 0, 0, 0);                                \
    acc31 = MFMA_(a3, b1v, acc31, 0, 0, 0);                                \
    __builtin_amdgcn_s_setprio(0);                                         \
    a0 = *(const half8*)((CB) + oA + 512);                                 \
    a1 = *(const half8*)((CB) + oA + 1536);                                \
    a2 = *(const half8*)((CB) + oA + 2560);                                \
    a3 = *(const half8*)((CB) + oA + 3584);                                \
    b0v = *(const half8*)((CB) + oB + 512);                                \
    b1v = *(const half8*)((CB) + oB + 1536);                               \
    __builtin_amdgcn_s_setprio(1);                                         \
    acc00 = MFMA_(a0, b0v, acc00, 0, 0, 0);                                \
    acc01 = MFMA_(a0, b1v, acc01, 0, 0, 0);                                \
    acc10 = MFMA_(a1, b0v, acc10, 0, 0, 0);                                \
    acc11 = MFMA_(a1, b1v, acc11, 0, 0, 0);                                \
    acc20 = MFMA_(a2, b0v, acc20, 0, 0, 0);                                \
    acc21 = MFMA_(a2, b1v, acc21, 0, 0, 0);                                \
    acc30 = MFMA_(a3, b0v, acc30, 0, 0, 0);                                \
    acc31 = MFMA_(a3, b1v, acc31, 0, 0, 0);                                \
    __builtin_amdgcn_s_setprio(0);                                         \
    if ((VW) == 6)      asm volatile("s_waitcnt vmcnt(6) lgkmcnt(0)" ::: "memory"); \
    else if ((VW) == 0) asm volatile("s_waitcnt vmcnt(0) lgkmcnt(0)" ::: "memory"); \
    else                asm volatile("s_waitcnt lgkmcnt(0)" ::: "memory"); \
    asm volatile("s_barrier" ::: "memory");                                \
  }

__global__ __launch_bounds__(256, 2) void gemm_qkv(
    const u16* __restrict__ Afrag, const u16* __restrict__ Bfrag,
    const float* __restrict__ bias, u16* __restrict__ qkvf)
{
    __shared__ u16 lds[3][12288];
    const int tid  = threadIdx.x;
    const int lane = tid & 63;
    const int wave = tid >> 6;
    const int wm   = wave >> 1;
    const int wn   = wave & 1;
    const int la8  = lane * 8;

    const int nb  = gridDim.x * gridDim.y;
    int bid = blockIdx.y * gridDim.x + blockIdx.x;
    bid = (bid & 7) * (nb >> 3) + (bid >> 3);
    const int bx = bid % gridDim.x;
    const int by = bid / gridDim.x;

    const u16* gA0 = Afrag + ((size_t)(by*8 + ((wave    )>>1))*64 + ((wave    )&1))*512 + la8;
    const u16* gA1 = Afrag + ((size_t)(by*8 + ((wave+ 4 )>>1))*64 + ((wave+ 4 )&1))*512 + la8;
    const u16* gA2 = Afrag + ((size_t)(by*8 + ((wave+ 8 )>>1))*64 + ((wave+ 8 )&1))*512 + la8;
    const u16* gA3 = Afrag + ((size_t)(by*8 + ((wave+12 )>>1))*64 + ((wave+12 )&1))*512 + la8;
    const u16* gB0 = Bfrag + ((size_t)(bx*4 + ((wave    )>>1))*64 + ((wave    )&1))*512 + la8;
    const u16* gB1 = Bfrag + ((size_t)(bx*4 + ((wave+ 4 )>>1))*64 + ((wave+ 4 )&1))*512 + la8;
    const int lA0 = (wave     ) * 512;
    const int lA1 = (wave +  4) * 512;
    const int lA2 = (wave +  8) * 512;
    const int lA3 = (wave + 12) * 512;
    const int lB0 = 8192 + (wave    ) * 512;
    const int lB1 = 8192 + (wave + 4) * 512;

    const int oA = wm * 4096 + la8;
    const int oB = 8192 + wn * 2048 + la8;

    u16* b0 = &lds[0][0];
    u16* b1 = &lds[1][0];
    u16* b2 = &lds[2][0];

    STAGE(b0, 0);
    STAGE(b1, 1);
    asm volatile("s_waitcnt vmcnt(6)" ::: "memory");
    asm volatile("s_barrier" ::: "memory");

    f32x16 acc00, acc01, acc10, acc11, acc20, acc21, acc30, acc31;
#pragma unroll
    for (int r = 0; r < 16; ++r) {
        acc00[r] = 0.f; acc01[r] = 0.f; acc10[r] = 0.f; acc11[r] = 0.f;
        acc20[r] = 0.f; acc21[r] = 0.f; acc30[r] = 0.f; acc31[r] = 0.f;
    }

#pragma unroll 1
    for (int kt = 0; kt < NT - 2; kt += 3) {
        TILE(b0, b2, kt,     1, 6);
        TILE(b1, b0, kt + 1, 1, 6);
        TILE(b2, b1, kt + 2, 1, 6);
    }
    TILE(b0, b2, NT - 2, 0, 0);
    TILE(b1, b2, NT - 1, 0, -1);

    // epilogue: scatter into attn operand layouts.
    // C/D: col = lane&31, row = (reg&3)+8*(reg>>2)+4*(lane>>5)  [m74/m101]
    const int m0 = by * 256 + wm * 128;
    const int n0 = bx * 128 + wn * 64;
    f32x16 accs[4][2] = {{acc00, acc01}, {acc10, acc11}, {acc20, acc21}, {acc30, acc31}};
#pragma unroll
    for (int i = 0; i < 4; ++i) {
#pragma unroll
        for (int j = 0; j < 2; ++j) {
            const int col = n0 + j * 32 + (lane & 31);
            const int mat = col >> 10;          // wave-uniform per (bx,j)
            const int ch  = col & 1023;
            const float bv = bias[col];
            u16* dst = qkvf + (size_t)mat * ((size_t)M_ * C_);
#pragma unroll
            for (int reg = 0; reg < 16; ++reg) {
                const int m = m0 + i * 32 + (reg & 3) + 8 * (reg >> 2) + 4 * (lane >> 5);
                _Float16 h = (_Float16)(accs[i][j][reg] + bv);
                size_t addr;
                if (mat < 2) {  // Q/K: A/B-frag-major
                    addr = (size_t)((m >> 5) * 64 + (ch >> 4)) * 512
                         + ((m & 31) + 32 * ((ch >> 3) & 1)) * 8 + (ch & 7);
                } else {        // V: token-fine k-slice frag
                    addr = (size_t)((m >> 4) * 32 + (ch >> 5)) * 512
                         + ((ch & 31) + 32 * ((m >> 3) & 1)) * 8 + (m & 7);
                }
                dst[addr] = __builtin_bit_cast(unsigned short, h);
            }
        }
    }
}

// ---------------- small-tile GEMM for Wo: BM=128 x BN=128 ----------------
#define STAGE_S0(NB, KO) { gload16(gA0 + (KO), (NB) + lsA0); gload16(gB0 + (KO), (NB) + lsB0); }
#define STAGE_S1(NB, KO) { gload16(gA1 + (KO), (NB) + lsA1); gload16(gB1 + (KO), (NB) + lsB1); }

#define TILE_S(CB, NB, KT, DOSTG, VW)                                      \
  {                                                                        \
    const size_t ko = (size_t)((KT) + 2) * 1024;                           \
    half8 a0 = *(const half8*)((CB) + oA);                                 \
    half8 a1 = *(const half8*)((CB) + oA + 1024);                          \
    half8 b0v = *(const half8*)((CB) + oB);                                \
    half8 b1v = *(const half8*)((CB) + oB + 1024);                         \
    if (DOSTG) STAGE_S0(NB, ko);                                           \
    __builtin_amdgcn_s_setprio(1);                                         \
    acc00 = MFMA_(a0, b0v, acc00, 0, 0, 0);                                \
    acc01 = MFMA_(a0, b1v, acc01, 0, 0, 0);                                \
    acc10 = MFMA_(a1, b0v, acc10, 0, 0, 0);                                \
    acc11 = MFMA_(a1, b1v, acc11, 0, 0, 0);                                \
    __builtin_amdgcn_s_setprio(0);                                         \
    a0 = *(const half8*)((CB) + oA + 512);                                 \
    a1 = *(const half8*)((CB) + oA + 1536);                                \
    b0v = *(const half8*)((CB) + oB + 512);                                \
    b1v = *(const half8*)((CB) + oB + 1536);                               \
    if (DOSTG) STAGE_S1(NB, ko);                                           \
    __builtin_amdgcn_s_setprio(1);                                         \
    acc00 = MFMA_(a0, b0v, acc00, 0, 0, 0);                                \
    acc01 = MFMA_(a0, b1v, acc01, 0, 0, 0);                                \
    acc10 = MFMA_(a1, b0v, acc10, 0, 0, 0);                                \
    acc11 = MFMA_(a1, b1v, acc11, 0, 0, 0);                                \
    __builtin_amdgcn_s_setprio(0);                                         \
    if ((VW) == 4)      asm volatile("s_waitcnt vmcnt(4) lgkmcnt(0)" ::: "memory"); \
    else if ((VW) == 0) asm volatile("s_waitcnt vmcnt(0) lgkmcnt(0)" ::: "memory"); \
    else                asm volatile("s_waitcnt lgkmcnt(0)" ::: "memory"); \
    asm volatile("s_barrier" ::: "memory");                                \
  }

__global__ __launch_bounds__(256, 2) void gemm_s(
    const u16* __restrict__ Afrag, const u16* __restrict__ Bfrag,
    const float* __restrict__ bias, float* __restrict__ Cout, int Ndim)
{
    __shared__ u16 lds[3][8192];
    const int tid  = threadIdx.x;
    const int lane = tid & 63;
    const int wave = tid >> 6;
    const int wm   = wave >> 1;
    const int wn   = wave & 1;
    const int la8  = lane * 8;

    const int nb  = gridDim.x * gridDim.y;
    int bid = blockIdx.y * gridDim.x + blockIdx.x;
    bid = (bid & 7) * (nb >> 3) + (bid >> 3);
    const int bx = bid % gridDim.x;
    const int by = bid / gridDim.x;

    const u16* gA0 = Afrag + ((size_t)(by*4 + ((wave    )>>1))*64 + ((wave    )&1))*512 + la8;
    const u16* gA1 = Afrag + ((size_t)(by*4 + ((wave+ 4 )>>1))*64 + ((wave+ 4 )&1))*512 + la8;
    const u16* gB0 = Bfrag + ((size_t)(bx*4 + ((wave    )>>1))*64 + ((wave    )&1))*512 + la8;
    const u16* gB1 = Bfrag + ((size_t)(bx*4 + ((wave+ 4 )>>1))*64 + ((wave+ 4 )&1))*512 + la8;
    const int lsA0 = (wave    ) * 512;
    const int lsA1 = (wave + 4) * 512;
    const int lsB0 = 4096 + (wave    ) * 512;
    const int lsB1 = 4096 + (wave + 4) * 512;

    const int oA = wm * 2048 + la8;
    const int oB = 4096 + wn * 2048 + la8;

    u16* b0 = &lds[0][0];
    u16* b1 = &lds[1][0];
    u16* b2 = &lds[2][0];

    STAGE_S0(b0, 0); STAGE_S1(b0, 0);
    STAGE_S0(b1, 1024); STAGE_S1(b1, 1024);
    asm volatile("s_waitcnt vmcnt(4)" ::: "memory");
    asm volatile("s_barrier" ::: "memory");

    f32x16 acc00, acc01, acc10, acc11;
#pragma unroll
    for (int r = 0; r < 16; ++r) { acc00[r] = 0.f; acc01[r] = 0.f; acc10[r] = 0.f; acc11[r] = 0.f; }

#pragma unroll 1
    for (int kt = 0; kt < NT - 2; kt += 3) {
        TILE_S(b0, b2, kt,     1, 4);
        TILE_S(b1, b0, kt + 1, 1, 4);
        TILE_S(b2, b1, kt + 2, 1, 4);
    }
    TILE_S(b0, b2, NT - 2, 0, 0);
    TILE_S(b1, b2, NT - 1, 0, -1);

    const int m0 = by * 128 + wm * 64;
    const int n0 = bx * 128 + wn * 64;
    f32x16 accs[2][2] = {{acc00, acc01}, {acc10, acc11}};
#pragma unroll
    for (int i = 0; i < 2; ++i) {
#pragma unroll
        for (int j = 0; j < 2; ++j) {
            const int col = n0 + j * 32 + (lane & 31);
            const float bv = bias[col];
#pragma unroll
            for (int reg = 0; reg < 16; ++reg) {
                const int row = m0 + i * 32 + (reg & 3) + 8 * (reg >> 2) + 4 * (lane >> 5);
                Cout[(size_t)row * Ndim + col] = accs[i][j][reg] + bv;
            }
        }
    }
}

// ---------------- MFMA windowed attention: 1 wave / 32 tokens -------------
// Swapped QK^T: S = mfma(A=K_rows, B=Q) -> lane owns score COLUMN q=lane&31
// with kv-rows in regs; one shfl_xor(.,32) per reg merges the half-split.
// Replaces the old 6-level x 17-offset shuffle softmax (the real attn cost).
// Two shifted K tiles [t0-16,t0+15], [t0+16,t0+47] cover every q's window.
// PV: out = mfma(A=P_f16, B=V-frag) over 4 token-16 k-slices x 32 ch-chunks.
__global__ __launch_bounds__(64) void attn_mfma(
    const u16* __restrict__ qf, const u16* __restrict__ kf,
    const u16* __restrict__ vf, u16* __restrict__ ctxf)
{
    const int l   = threadIdx.x;
    const int q   = l & 31;
    const int hi  = l >> 5;
    const int t0  = blockIdx.x * 32;
    const int t0l = t0 & (T_ - 1);

    // ---- QK^T ----
    const int r1 = min(max(t0 - 16 + q, 0), M_ - 1);
    const int r2 = min(max(t0 + 16 + q, 0), M_ - 1);
    const u16* a1p = kf + (size_t)(r1 >> 5) * 32768 + ((r1 & 31) + 32 * hi) * 8;
    const u16* a2p = kf + (size_t)(r2 >> 5) * 32768 + ((r2 & 31) + 32 * hi) * 8;
    const u16* qp  = qf + (size_t)(t0 >> 5) * 32768 + l * 8;

    f32x16 sc1, sc2;
#pragma unroll
    for (int r = 0; r < 16; ++r) { sc1[r] = 0.f; sc2[r] = 0.f; }
#pragma unroll 8
    for (int ks = 0; ks < 64; ++ks) {
        half8 a1 = *(const half8*)(a1p + ks * 512);
        half8 a2 = *(const half8*)(a2p + ks * 512);
        half8 qb = *(const half8*)(qp  + ks * 512);
        sc1 = MFMA_(a1, qb, sc1, 0, 0, 0);
        sc2 = MFMA_(a2, qb, sc2, 0, 0, 0);
    }

    // ---- merge half-split columns: partner regs via lane^32 ----
    float px1[16], px2[16];
#pragma unroll
    for (int r = 0; r < 16; ++r) {
        px1[r] = __shfl_xor(sc1[r], 32);
        px2[r] = __shfl_xor(sc2[r], 32);
    }

    // ---- assemble s[p], p = j_abs - (t0-16) in [0,64); mask + scale ----
    // C row = (reg&3)+8*(reg>>2)+4*h  ->  given row: h=(row>>2)&1,
    // reg=(row&3)+4*(row>>3). All indices static; only selects are runtime.
    const int plo = max(q + 8, 16 - t0l);
    const int phi = min(q + 24, (T_ + 15) - t0l);   // jl<=T_-1 -> p<=2063-t0l
    float s[64];
#pragma unroll
    for (int p = 0; p < 64; ++p) {
        const int row = p & 31;
        const int h   = (row >> 2) & 1;
        const int rg  = (row & 3) + 4 * (row >> 3);
        const float own = (p < 32) ? sc1[rg] : sc2[rg];
        const float oth = (p < 32) ? px1[rg] : px2[rg];
        const float v = (h == hi) ? own : oth;
        s[p] = (p >= plo && p <= phi) ? v * 0.03125f : -3.0e38f;
    }

    // ---- per-lane softmax over 64 regs (17 valid) ----
    float mx = s[0];
#pragma unroll
    for (int p = 1; p < 64; ++p) mx = fmaxf(mx, s[p]);
    float den = 0.f;
#pragma unroll
    for (int p = 0; p < 64; ++p) { const float w = __expf(s[p] - mx); s[p] = w; den += w; }
    const float inv = 1.f / den;

    // ---- pack P -> fp16 A-frags (runtime hi-select, static indices) ----
    half8 pa0, pa1, pa2, pa3;
#pragma unroll
    for (int e = 0; e < 8; ++e) {
        pa0[e] = (_Float16)((hi ? s[ 8 + e] : s[ 0 + e]) * inv);
        pa1[e] = (_Float16)((hi ? s[24 + e] : s[16 + e]) * inv);
        pa2[e] = (_Float16)((hi ? s[40 + e] : s[32 + e]) * inv);
        pa3[e] = (_Float16)((hi ? s[56 + e] : s[48 + e]) * inv);
    }

    // ---- PV: 4 k-slices x 32 col-chunks; epilogue -> ctxf frag-major ----
    const int s0i = (t0 - 16) >> 4;
    const u16* vb0p = vf + (size_t)min(max(s0i    , 0), M_/16 - 1) * 16384 + l * 8;
    const u16* vb1p = vf + (size_t)min(max(s0i + 1, 0), M_/16 - 1) * 16384 + l * 8;
    const u16* vb2p = vf + (size_t)min(max(s0i + 2, 0), M_/16 - 1) * 16384 + l * 8;
    const u16* vb3p = vf + (size_t)min(max(s0i + 3, 0), M_/16 - 1) * 16384 + l * 8;
    const size_t ctxb = (size_t)(t0 >> 5) * 32768;
    const int lpo = 32 * ((l >> 3) & 1);
    const int e7  = l & 7;
#pragma unroll 2
    for (int n = 0; n < 32; ++n) {
        half8 v0 = *(const half8*)(vb0p + n * 512);
        half8 v1 = *(const half8*)(vb1p + n * 512);
        half8 v2 = *(const half8*)(vb2p + n * 512);
        half8 v3 = *(const half8*)(vb3p + n * 512);
        f32x16 o;
#pragma unroll
        for (int r = 0; r < 16; ++r) o[r] = 0.f;
        o = MFMA_(pa0, v0, o, 0, 0, 0);
        o = MFMA_(pa1, v1, o, 0, 0, 0);
        o = MFMA_(pa2, v2, o, 0, 0, 0);
        o = MFMA_(pa3, v3, o, 0, 0, 0);
        // out[q=rowmap(reg)][ch=32n+q'=32n+(l&31)] -> ctx frag-major
        u16* cp = ctxf + ctxb + (size_t)(2 * n + (q >> 4)) * 512 + e7;
#pragma unroll
        for (int r = 0; r < 16; ++r) {
            const int mrow = (r & 3) + 8 * (r >> 2) + 4 * hi;
            _Float16 hv = (_Float16)o[r];
            cp[(mrow + lpo) * 8] = __builtin_bit_cast(unsigned short, hv);
        }
    }
}

// ---------------- host launch ----------------
extern "C" void kernel_launch(void* const* d_in, const int* in_sizes, int n_in,
                              void* d_out, int out_size, void* d_ws, size_t ws_size,
                              hipStream_t stream) {
    const float* x  = (const float*)d_in[0];
    const float* Wq = (const float*)d_in[1];
    const float* bq = (const float*)d_in[2];
    const float* Wk = (const float*)d_in[3];
    const float* bk = (const float*)d_in[4];
    const float* Wv = (const float*)d_in[5];
    const float* bv = (const float*)d_in[6];
    const float* Wo = (const float*)d_in[7];
    const float* bo = (const float*)d_in[8];
    float* out = (float*)d_out;

    const size_t MC = (size_t)M_ * C_;              // 8M
    u16* xf   = (u16*)d_ws;                         // 8M  (x frag-major)
    u16* wfq  = xf   + MC;                          // 3M  (Wq;Wk;Wv frag-major)
    u16* wfo  = wfq  + 3 * (size_t)C_ * C_;         // 1M  (Wo frag-major)
    u16* qkvf = wfo  + (size_t)C_ * C_;             // 24M (qf | kf | vf)
    u16* ctxf = qkvf + 3 * MC;                      // 8M  (frag-major)
    float* bcat = (float*)(ctxf + MC);              // 3072 floats

    prologue2<<<3084, 256, 0, stream>>>(x, Wq, Wk, Wv, Wo, bq, bk, bv,
                                        xf, wfq, wfo, bcat);

    dim3 gqkv(3072 / 128, M_ / 256);   // (24, 32) = 768 blocks, 2/CU
    gemm_qkv<<<gqkv, 256, 0, stream>>>(xf, wfq, bcat, qkvf);

    attn_mfma<<<M_ / 32, 64, 0, stream>>>(qkvf, qkvf + MC, qkvf + 2 * MC, ctxf);

    dim3 go(C_ / 128, M_ / 128);       // (8, 64) = 512 blocks, 2/CU
    gemm_s<<<go, 256, 0, stream>>>(ctxf, wfo, bo, out, C_);
}

// Round 7
// 223.897 us; speedup vs baseline: 1.1305x; 1.1305x over previous
//
#include <hip/hip_runtime.h>
#include <cstdint>
#include <cstddef>

#define B_ 4
#define T_ 2048
#define C_ 1024
#define M_ (B_ * T_)   // 8192 rows
#define HALF_ 8
#define W_ 17
#define QKV_STRIDE 3072
#define NT 32          // K-tiles of BK=32 (gemm_p2)
#define NT8 16         // K-tiles of BK=64 (gemm8)

typedef unsigned short u16;
typedef _Float16 half8 __attribute__((ext_vector_type(8)));
typedef _Float16 half2_t __attribute__((ext_vector_type(2)));
typedef float f32x16 __attribute__((ext_vector_type(16)));
typedef unsigned short ushort8v __attribute__((ext_vector_type(8)));

__device__ __forceinline__ float dot16(half8 a, half8 b, float acc) {
#if __has_builtin(__builtin_amdgcn_fdot2)
    const half2_t* pa = (const half2_t*)&a;
    const half2_t* pb = (const half2_t*)&b;
#pragma unroll
    for (int e = 0; e < 4; ++e) acc = __builtin_amdgcn_fdot2(pa[e], pb[e], acc, false);
#else
#pragma unroll
    for (int e = 0; e < 8; ++e) acc += (float)a[e] * (float)b[e];
#endif
    return acc;
}

__device__ __forceinline__ ushort4 cvt4(float4 v) {
    ushort4 o;
    _Float16 a = (_Float16)v.x; o.x = __builtin_bit_cast(unsigned short, a);
    _Float16 b = (_Float16)v.y; o.y = __builtin_bit_cast(unsigned short, b);
    _Float16 c = (_Float16)v.z; o.z = __builtin_bit_cast(unsigned short, c);
    _Float16 d = (_Float16)v.w; o.w = __builtin_bit_cast(unsigned short, d);
    return o;
}

// ================= fragment-major layout =================
// chunk (mt, ks) = 1KB at ((mt*64 + ks)*512) u16; lane l holds
// Mat[row = mt*32 + (l&31)][k = ks*16 + (l>>5)*8 + e]. Conflict-free
// ds_read_b128 at lane*16B; gload_lds-native (wave-uniform dst + lane*16B).

// ---------------- prologue: coalesced LDS-transpose to frag-major --------
__global__ void prologue2(const float* __restrict__ x,
                          const float* __restrict__ Wq, const float* __restrict__ Wk,
                          const float* __restrict__ Wv, const float* __restrict__ Wo,
                          const float* __restrict__ bq, const float* __restrict__ bk,
                          const float* __restrict__ bv,
                          u16* __restrict__ xf, u16* __restrict__ wfq,
                          u16* __restrict__ wfo, float* __restrict__ bcat) {
    const int blk = blockIdx.x;
    const int tid = threadIdx.x;
    if (blk >= 3072) {
        int i = (blk - 3072) * 256 + tid;
        const float* src = (i < 1024) ? bq : (i < 2048) ? bk : bv;
        bcat[i] = src[i & 1023];
        return;
    }
    __shared__ ushort8v g16[512];
    const float* src;
    u16* dst;
    size_t chunk_base;
    int kg;
    if (blk < 2048) {
        const int mt = blk >> 3; kg = blk & 7;
        src = x + (size_t)mt * 32 * C_;
        dst = xf; chunk_base = (size_t)mt * 64;
    } else {
        const int w = blk - 2048;
        const int mat = w >> 8, nt = (w >> 3) & 31; kg = w & 7;
        src = ((mat == 0) ? Wq : (mat == 1) ? Wk : (mat == 2) ? Wv : Wo)
              + (size_t)nt * 32 * C_;
        if (mat < 3) { dst = wfq; chunk_base = (size_t)(mat * 32 + nt) * 64; }
        else         { dst = wfo; chunk_base = (size_t)nt * 64; }
    }
    const int r = tid >> 3, gc = (tid & 7) * 2;
    const float4* s4 = (const float4*)(src + (size_t)r * C_ + kg * 128 + (tid & 7) * 16);
    float4 f0 = s4[0], f1 = s4[1], f2 = s4[2], f3 = s4[3];
    ushort4 h0 = cvt4(f0), h1 = cvt4(f1), h2 = cvt4(f2), h3 = cvt4(f3);
    ushort8v ga, gb;
    ga[0]=h0.x; ga[1]=h0.y; ga[2]=h0.z; ga[3]=h0.w;
    ga[4]=h1.x; ga[5]=h1.y; ga[6]=h1.z; ga[7]=h1.w;
    gb[0]=h2.x; gb[1]=h2.y; gb[2]=h2.z; gb[3]=h2.w;
    gb[4]=h3.x; gb[5]=h3.y; gb[6]=h3.z; gb[7]=h3.w;
    g16[r * 16 + ((gc    ) ^ (r & 15))] = ga;
    g16[r * 16 + ((gc + 1) ^ (r & 15))] = gb;
    __syncthreads();
    const int lane = tid & 63, rr = lane & 31, hi = lane >> 5;
#pragma unroll
    for (int r2 = 0; r2 < 2; ++r2) {
        const int ksl = r2 * 4 + (tid >> 6);
        const int g = ksl * 2 + hi;
        ushort8v v = g16[rr * 16 + (g ^ (rr & 15))];
        *(ushort8v*)(dst + ((chunk_base + kg * 8 + ksl) * 64 + lane) * 8) = v;
    }
}

#define AS1_ __attribute__((address_space(1)))
#define AS3_ __attribute__((address_space(3)))

__device__ __forceinline__ void gload16(const u16* g, u16* l) {
    __builtin_amdgcn_global_load_lds((AS1_ void*)g, (AS3_ void*)l, 16, 0, 0);
}

#define MFMA_ __builtin_amdgcn_mfma_f32_32x32x16_f16
#define BAR_  asm volatile("s_barrier" ::: "memory")
#define WL0_  asm volatile("s_waitcnt lgkmcnt(0)" ::: "memory")
#define WV4_  asm volatile("s_waitcnt vmcnt(4)" ::: "memory")
#define WV0_  asm volatile("s_waitcnt vmcnt(0)" ::: "memory")
#define LD8_(p) (*(const half8*)(p))

// ================= gemm8: 8-phase counted-vmcnt QKV GEMM =================
// BM=256 x BN=256 x BK=64; 8 waves (2M x 4N), wave tile 128x64, acc 4x2.
// LDS: 2 buffers x (A 32KB + B 32KB) = 128KB -> 1 block/CU.
// Per K-tile: 8 phases, each {2-4 ds_read ; 1 gload_lds(next tile) ;
// s_barrier ; lgkmcnt(0) ; setprio(1) 4xMFMA setprio(0) ; s_barrier}.
// Half-tile staging: h1 chunks (ksl 0,1) issued phases 0-3, h2 phases 4-7;
// vmcnt(4) at phase 3 (certifies current h2, leaves next h1 in flight) and
// phase 7 (certifies next h1, leaves next h2 in flight) -- NEVER drains.
// This is the documented T3+T4 escape from the ~36% MfmaUtil 2-barrier
// structure ceiling; T2 swizzle unnecessary (frag chunks conflict-free).

// phase with 4 A/B reads (h=0) -- MFMAs m in {0,1}
#define PH8_A(CB, SB, KSO, GS, LS, DOSTG, KO)                              \
  { rA0 = LD8_((CB) + oA0 + (KSO)); rA1 = LD8_((CB) + oA1 + (KSO));        \
    rB0 = LD8_((CB) + oB0 + (KSO)); rB1 = LD8_((CB) + oB1 + (KSO));        \
    if (DOSTG) gload16(GS + (KO), (SB) + LS);                              \
    BAR_; WL0_;                                                            \
    __builtin_amdgcn_s_setprio(1);                                         \
    acc00 = MFMA_(rA0, rB0, acc00, 0, 0, 0);                               \
    acc01 = MFMA_(rA0, rB1, acc01, 0, 0, 0);                               \
    acc10 = MFMA_(rA1, rB0, acc10, 0, 0, 0);                               \
    acc11 = MFMA_(rA1, rB1, acc11, 0, 0, 0);                               \
    __builtin_amdgcn_s_setprio(0); }

// phase with 2 A reads (h=1, reuses rB0/rB1) -- MFMAs m in {2,3}
#define PH8_B(CB, SB, KSO, GS, LS, DOSTG, KO)                              \
  { rA2 = LD8_((CB) + oA2 + (KSO)); rA3 = LD8_((CB) + oA3 + (KSO));        \
    if (DOSTG) gload16(GS + (KO), (SB) + LS);                              \
    BAR_; WL0_;                                                            \
    __builtin_amdgcn_s_setprio(1);                                         \
    acc20 = MFMA_(rA2, rB0, acc20, 0, 0, 0);                               \
    acc21 = MFMA_(rA2, rB1, acc21, 0, 0, 0);                               \
    acc30 = MFMA_(rA3, rB0, acc30, 0, 0, 0);                               \
    acc31 = MFMA_(rA3, rB1, acc31, 0, 0, 0);                               \
    __builtin_amdgcn_s_setprio(0); }

// full K-tile: TAIL=0 normal (vmcnt4 at p3/p7), TAIL=1 last (vmcnt0 at p3)
#define TILE8(CB, SB, KO, DOSTG, TAIL)                                     \
  { half8 rA0, rA1, rA2, rA3, rB0, rB1;                                    \
    PH8_A(CB, SB,    0, gs0, ls0, DOSTG, KO); BAR_;                        \
    PH8_B(CB, SB,    0, gs1, ls1, DOSTG, KO); BAR_;                        \
    PH8_A(CB, SB,  512, gs2, ls2, DOSTG, KO); BAR_;                        \
    PH8_B(CB, SB,  512, gs3, ls3, DOSTG, KO);                              \
    if (TAIL) { WV0_; } else { WV4_; } BAR_;                               \
    PH8_A(CB, SB, 1024, gs4, ls4, DOSTG, KO); BAR_;                        \
    PH8_B(CB, SB, 1024, gs5, ls5, DOSTG, KO); BAR_;                        \
    PH8_A(CB, SB, 1536, gs6, ls6, DOSTG, KO); BAR_;                        \
    PH8_B(CB, SB, 1536, gs7, ls7, DOSTG, KO);                              \
    if (!TAIL) { WV4_; BAR_; } }

__global__ __launch_bounds__(512, 1) void gemm8(
    const u16* __restrict__ Afrag, const u16* __restrict__ Bfrag,
    const float* __restrict__ bias, u16* __restrict__ Cout)
{
    __shared__ u16 lds[2][32768];   // 2 x 64KB
    const int tid  = threadIdx.x;
    const int lane = tid & 63;
    const int w    = tid >> 6;      // 0..7
    const int wm   = w >> 2;        // 0..1 (M half: 128 rows)
    const int wn   = w & 3;         // 0..3 (N quarter: 64 cols)
    const int la8  = lane * 8;

    // bijective XCD swizzle (384 % 8 == 0)
    const int nb  = gridDim.x * gridDim.y;
    int bid = blockIdx.y * gridDim.x + blockIdx.x;
    bid = (bid & 7) * (nb >> 3) + (bid >> 3);
    const int bx = bid % gridDim.x;
    const int by = bid / gridDim.x;

    // staging map: wave w, slot s (0..3), half h: cidx = s*8 + w
    //   s 0,1 -> A (mt_l = cidx>>1, ksl = (cidx&1)+2h)
    //   s 2,3 -> B (nt_l = (cidx-16)>>1, ksl = ((cidx-16)&1)+2h)
    const int w2 = w >> 1, w1 = w & 1;
    const u16* gs0 = Afrag + ((size_t)(by*8 +     w2)*64 + (w1    ))*512 + la8;
    const u16* gs1 = Afrag + ((size_t)(by*8 + 4 + w2)*64 + (w1    ))*512 + la8;
    const u16* gs2 = Bfrag + ((size_t)(bx*8 +     w2)*64 + (w1    ))*512 + la8;
    const u16* gs3 = Bfrag + ((size_t)(bx*8 + 4 + w2)*64 + (w1    ))*512 + la8;
    const u16* gs4 = Afrag + ((size_t)(by*8 +     w2)*64 + (w1 + 2))*512 + la8;
    const u16* gs5 = Afrag + ((size_t)(by*8 + 4 + w2)*64 + (w1 + 2))*512 + la8;
    const u16* gs6 = Bfrag + ((size_t)(bx*8 +     w2)*64 + (w1 + 2))*512 + la8;
    const u16* gs7 = Bfrag + ((size_t)(bx*8 + 4 + w2)*64 + (w1 + 2))*512 + la8;
    // LDS chunk bases (wave-uniform): A (mt_l*4+ksl)*512 ; B 16384 + same
    const int ls0 = ((    w2)*4 + (w1    ))*512;
    const int ls1 = ((4 + w2)*4 + (w1    ))*512;
    const int ls2 = 16384 + ((    w2)*4 + (w1    ))*512;
    const int ls3 = 16384 + ((4 + w2)*4 + (w1    ))*512;
    const int ls4 = ((    w2)*4 + (w1 + 2))*512;
    const int ls5 = ((4 + w2)*4 + (w1 + 2))*512;
    const int ls6 = 16384 + ((    w2)*4 + (w1 + 2))*512;
    const int ls7 = 16384 + ((4 + w2)*4 + (w1 + 2))*512;

    // consumer offsets: A chunk (4wm+i, ks) ; B chunk (2wn+j, ks)
    const int oA0 = (4*wm    )*2048 + la8;
    const int oA1 = (4*wm + 1)*2048 + la8;
    const int oA2 = (4*wm + 2)*2048 + la8;
    const int oA3 = (4*wm + 3)*2048 + la8;
    const int oB0 = 16384 + (2*wn    )*2048 + la8;
    const int oB1 = 16384 + (2*wn + 1)*2048 + la8;

    u16* b0 = &lds[0][0];
    u16* b1 = &lds[1][0];

    // prologue: stage tile 0 fully (h1 first); vmcnt(4) certifies h1
    gload16(gs0, b0 + ls0); gload16(gs1, b0 + ls1);
    gload16(gs2, b0 + ls2); gload16(gs3, b0 + ls3);
    gload16(gs4, b0 + ls4); gload16(gs5, b0 + ls5);
    gload16(gs6, b0 + ls6); gload16(gs7, b0 + ls7);
    WV4_; BAR_;

    f32x16 acc00, acc01, acc10, acc11, acc20, acc21, acc30, acc31;
#pragma unroll
    for (int r = 0; r < 16; ++r) {
        acc00[r] = 0.f; acc01[r] = 0.f; acc10[r] = 0.f; acc11[r] = 0.f;
        acc20[r] = 0.f; acc21[r] = 0.f; acc30[r] = 0.f; acc31[r] = 0.f;
    }

    // tile t in buf[t&1]; while computing t, stage t+1 into buf[(t+1)&1]
#pragma unroll 1
    for (int t = 0; t < NT8 - 2; t += 2) {
        TILE8(b0, b1, (size_t)(t + 1) * 2048, 1, 0);
        TILE8(b1, b0, (size_t)(t + 2) * 2048, 1, 0);
    }
    TILE8(b0, b1, (size_t)(NT8 - 1) * 2048, 1, 0);  // t=14, stage t15
    TILE8(b1, b0, 0, 0, 1);                          // t=15, tail

    // epilogue: row-major fp16 (coalesced 64B runs; proven write pattern)
    // C/D: col = lane&31, row = (reg&3)+8*(reg>>2)+4*(lane>>5)  [m74/m101]
    const int m0 = by * 256 + wm * 128;
    const int n0 = bx * 256 + wn * 64;
    f32x16 accs[4][2] = {{acc00, acc01}, {acc10, acc11}, {acc20, acc21}, {acc30, acc31}};
#pragma unroll
    for (int i = 0; i < 4; ++i) {
#pragma unroll
        for (int j = 0; j < 2; ++j) {
            const int col = n0 + j * 32 + (lane & 31);
            const float bv = bias[col];
#pragma unroll
            for (int reg = 0; reg < 16; ++reg) {
                const int row = m0 + i * 32 + (reg & 3) + 8 * (reg >> 2) + 4 * (lane >> 5);
                _Float16 h = (_Float16)(accs[i][j][reg] + bv);
                Cout[(size_t)row * QKV_STRIDE + col] = __builtin_bit_cast(unsigned short, h);
            }
        }
    }
}

// ---------------- gemm_p2 (round-2 proven) for Wo ----------------
#define STAGE(NB, KT) { const size_t ko = (size_t)(KT) * 1024;            \
    gload16(gA0 + ko, (NB) + lA0); gload16(gA1 + ko, (NB) + lA1);         \
    gload16(gA2 + ko, (NB) + lA2); gload16(gA3 + ko, (NB) + lA3);         \
    gload16(gB0 + ko, (NB) + lB0); gload16(gB1 + ko, (NB) + lB1); }

#define TILE(CB, NB, KT, DOSTG, VW)                                        \
  {                                                                        \
    half8 a0 = *(const half8*)((CB) + oA);                                 \
    half8 a1 = *(const half8*)((CB) + oA + 1024);                          \
    half8 a2 = *(const half8*)((CB) + oA + 2048);                          \
    half8 a3 = *(const half8*)((CB) + oA + 3072);                          \
    half8 b0v = *(const half8*)((CB) + oB);                                \
    half8 b1v = *(const half8*)((CB) + oB + 1024);                         \
    if (DOSTG) STAGE(NB, (KT) + 2);                                        \
    __builtin_amdgcn_s_setprio(1);                                         \
    acc00 = MFMA_(a0, b0v, acc00, 0, 0, 0);                                \
    acc01 = MFMA_(a0, b1v, acc01, 0, 0, 0);                                \
    acc10 = MFMA_(a1, b0v, acc10, 0, 0, 0);                                \
    acc11 = MFMA_(a1, b1v, acc11, 0, 0, 0);                                \
    acc20 = MFMA_(a2, b0v, acc20, 0, 0, 0);                                \
    acc21 = MFMA_(a2, b1v, acc21, 0, 0, 0);                                \
    acc30 = MFMA_(a3, b0v, acc30, 0, 0, 0);                                \
    acc31 = MFMA_(a3, b1v, acc31, 0, 0, 0);                                \
    __builtin_amdgcn_s_setprio(0);                                         \
    a0 = *(const half8*)((CB) + oA + 512);                                 \
    a1 = *(const half8*)((CB) + oA + 1536);                                \
    a2 = *(const half8*)((CB) + oA + 2560);                                \
    a3 = *(const half8*)((CB) + oA + 3584);                                \
    b0v = *(const half8*)((CB) + oB + 512);                                \
    b1v = *(const half8*)((CB) + oB + 1536);                               \
    __builtin_amdgcn_s_setprio(1);                                         \
    acc00 = MFMA_(a0, b0v, acc00, 0, 0, 0);                                \
    acc01 = MFMA_(a0, b1v, acc01, 0, 0, 0);                                \
    acc10 = MFMA_(a1, b0v, acc10, 0, 0, 0);                                \
    acc11 = MFMA_(a1, b1v, acc11, 0, 0, 0);                                \
    acc20 = MFMA_(a2, b0v, acc20, 0, 0, 0);                                \
    acc21 = MFMA_(a2, b1v, acc21, 0, 0, 0);                                \
    acc30 = MFMA_(a3, b0v, acc30, 0, 0, 0);                                \
    acc31 = MFMA_(a3, b1v, acc31, 0, 0, 0);                                \
    __builtin_amdgcn_s_setprio(0);                                         \
    if ((VW) == 6)      asm volatile("s_waitcnt vmcnt(6) lgkmcnt(0)" ::: "memory"); \
    else if ((VW) == 0) asm volatile("s_waitcnt vmcnt(0) lgkmcnt(0)" ::: "memory"); \
    else                asm volatile("s_waitcnt lgkmcnt(0)" ::: "memory"); \
    asm volatile("s_barrier" ::: "memory");                                \
  }

template <int OUT_F16>
__global__ __launch_bounds__(256, 2) void gemm_p2(
    const u16* __restrict__ Afrag, const u16* __restrict__ Bfrag,
    const float* __restrict__ bias, void* __restrict__ Cout, int Ndim)
{
    __shared__ u16 lds[3][12288];
    const int tid  = threadIdx.x;
    const int lane = tid & 63;
    const int wave = tid >> 6;
    const int wm   = wave >> 1;
    const int wn   = wave & 1;
    const int la8  = lane * 8;

    const int nb  = gridDim.x * gridDim.y;
    int bid = blockIdx.y * gridDim.x + blockIdx.x;
    bid = (bid & 7) * (nb >> 3) + (bid >> 3);
    const int bx = bid % gridDim.x;
    const int by = bid / gridDim.x;

    const u16* gA0 = Afrag + ((size_t)(by*8 + ((wave    )>>1))*64 + ((wave    )&1))*512 + la8;
    const u16* gA1 = Afrag + ((size_t)(by*8 + ((wave+ 4 )>>1))*64 + ((wave+ 4 )&1))*512 + la8;
    const u16* gA2 = Afrag + ((size_t)(by*8 + ((wave+ 8 )>>1))*64 + ((wave+ 8 )&1))*512 + la8;
    const u16* gA3 = Afrag + ((size_t)(by*8 + ((wave+12 )>>1))*64 + ((wave+12 )&1))*512 + la8;
    const u16* gB0 = Bfrag + ((size_t)(bx*4 + ((wave    )>>1))*64 + ((wave    )&1))*512 + la8;
    const u16* gB1 = Bfrag + ((size_t)(bx*4 + ((wave+ 4 )>>1))*64 + ((wave+ 4 )&1))*512 + la8;
    const int lA0 = (wave     ) * 512;
    const int lA1 = (wave +  4) * 512;
    const int lA2 = (wave +  8) * 512;
    const int lA3 = (wave + 12) * 512;
    const int lB0 = 8192 + (wave    ) * 512;
    const int lB1 = 8192 + (wave + 4) * 512;

    const int oA = wm * 4096 + la8;
    const int oB = 8192 + wn * 2048 + la8;

    u16* b0 = &lds[0][0];
    u16* b1 = &lds[1][0];
    u16* b2 = &lds[2][0];

    STAGE(b0, 0);
    STAGE(b1, 1);
    asm volatile("s_waitcnt vmcnt(6)" ::: "memory");
    asm volatile("s_barrier" ::: "memory");

    f32x16 acc00, acc01, acc10, acc11, acc20, acc21, acc30, acc31;
#pragma unroll
    for (int r = 0; r < 16; ++r) {
        acc00[r] = 0.f; acc01[r] = 0.f; acc10[r] = 0.f; acc11[r] = 0.f;
        acc20[r] = 0.f; acc21[r] = 0.f; acc30[r] = 0.f; acc31[r] = 0.f;
    }

#pragma unroll 1
    for (int kt = 0; kt < NT - 2; kt += 3) {
        TILE(b0, b2, kt,     1, 6);
        TILE(b1, b0, kt + 1, 1, 6);
        TILE(b2, b1, kt + 2, 1, 6);
    }
    TILE(b0, b2, NT - 2, 0, 0);
    TILE(b1, b2, NT - 1, 0, -1);

    const int m0 = by * 256 + wm * 128;
    const int n0 = bx * 128 + wn * 64;
    f32x16 accs[4][2] = {{acc00, acc01}, {acc10, acc11}, {acc20, acc21}, {acc30, acc31}};
#pragma unroll
    for (int i = 0; i < 4; ++i) {
#pragma unroll
        for (int j = 0; j < 2; ++j) {
            const int col = n0 + j * 32 + (lane & 31);
            const float bv = bias[col];
#pragma unroll
            for (int reg = 0; reg < 16; ++reg) {
                const int row = m0 + i * 32 + (reg & 3) + 8 * (reg >> 2) + 4 * (lane >> 5);
                float val = accs[i][j][reg] + bv;
                if (OUT_F16) {
                    _Float16 h = (_Float16)val;
                    ((u16*)Cout)[(size_t)row * Ndim + col] = __builtin_bit_cast(unsigned short, h);
                } else {
                    ((float*)Cout)[(size_t)row * Ndim + col] = val;
                }
            }
        }
    }
}

// ---------------- windowed attention (round-2 proven) ----------------
__global__ __launch_bounds__(256) void attn_local(
    const u16* __restrict__ qkv, u16* __restrict__ ctxf)
{
    const int wid  = blockIdx.x * 4 + (threadIdx.x >> 6);
    const int lane = threadIdx.x & 63;
    const int b = wid >> 11;
    const int t = wid & (T_ - 1);
    const int base = b * T_;
    const size_t qrow = (size_t)(base + t) * QKV_STRIDE;
    const int c0 = lane * 8;

    half8 q0 = *(const half8*)(qkv + qrow + c0);
    half8 q1 = *(const half8*)(qkv + qrow + 512 + c0);

    float s[W_];
#pragma unroll
    for (int o = 0; o < W_; ++o) {
        int j = t - HALF_ + o;
        int jc = min(max(j, 0), T_ - 1);
        const size_t kb = (size_t)(base + jc) * QKV_STRIDE + 1024;
        half8 k0v = *(const half8*)(qkv + kb + c0);
        half8 k1v = *(const half8*)(qkv + kb + 512 + c0);
        float d = dot16(q1, k1v, dot16(q0, k0v, 0.f));
#pragma unroll
        for (int off = 32; off > 0; off >>= 1)
            d += __shfl_xor(d, off);
        s[o] = (j == jc) ? d * 0.03125f : -3.0e38f;
    }

    float mx = s[0];
#pragma unroll
    for (int o = 1; o < W_; ++o) mx = fmaxf(mx, s[o]);
    float den = 0.f;
#pragma unroll
    for (int o = 0; o < W_; ++o) den += __expf(s[o] - mx);
    const float inv = 1.f / den;

    float acc0[8], acc1[8];
#pragma unroll
    for (int e = 0; e < 8; ++e) { acc0[e] = 0.f; acc1[e] = 0.f; }
#pragma unroll
    for (int o = 0; o < W_; ++o) {
        int j = t - HALF_ + o;
        int jc = min(max(j, 0), T_ - 1);
        const float wt = __expf(s[o] - mx) * inv;
        const size_t vb_ = (size_t)(base + jc) * QKV_STRIDE + 2048;
        half8 v0 = *(const half8*)(qkv + vb_ + c0);
        half8 v1 = *(const half8*)(qkv + vb_ + 512 + c0);
#pragma unroll
        for (int e = 0; e < 8; ++e) {
            acc0[e] += wt * (float)v0[e];
            acc1[e] += wt * (float)v1[e];
        }
    }

    half8 o0, o1;
#pragma unroll
    for (int e = 0; e < 8; ++e) { o0[e] = (_Float16)acc0[e]; o1[e] = (_Float16)acc1[e]; }

    const int m = base + t;
    const int mt = m >> 5;
    const int rowin = (m & 31) + 32 * (lane & 1);
    const size_t ch0 = ((size_t)mt * 64 + (lane >> 1)) * 64 + rowin;
    const size_t ch1 = ((size_t)mt * 64 + 32 + (lane >> 1)) * 64 + rowin;
    *(half8*)(ctxf + ch0 * 8) = o0;
    *(half8*)(ctxf + ch1 * 8) = o1;
}

// ---------------- host launch ----------------
extern "C" void kernel_launch(void* const* d_in, const int* in_sizes, int n_in,
                              void* d_out, int out_size, void* d_ws, size_t ws_size,
                              hipStream_t stream) {
    const float* x  = (const float*)d_in[0];
    const float* Wq = (const float*)d_in[1];
    const float* bq = (const float*)d_in[2];
    const float* Wk = (const float*)d_in[3];
    const float* bk = (const float*)d_in[4];
    const float* Wv = (const float*)d_in[5];
    const float* bv = (const float*)d_in[6];
    const float* Wo = (const float*)d_in[7];
    const float* bo = (const float*)d_in[8];
    float* out = (float*)d_out;

    u16* xf   = (u16*)d_ws;                         // 8M halves (frag-major)
    u16* wfq  = xf   + (size_t)M_ * C_;             // 3M  (Wq;Wk;Wv frag-major)
    u16* wfo  = wfq  + (size_t)3 * C_ * C_;         // 1M  (Wo frag-major)
    u16* qkvh = wfo  + (size_t)C_ * C_;             // 24M (M x 3072 row-major)
    u16* ctxf = qkvh + (size_t)M_ * QKV_STRIDE;     // 8M  (frag-major)
    float* bcat = (float*)(ctxf + (size_t)M_ * C_); // 3072 floats

    prologue2<<<3084, 256, 0, stream>>>(x, Wq, Wk, Wv, Wo, bq, bk, bv,
                                        xf, wfq, wfo, bcat);

    dim3 gqkv(QKV_STRIDE / 256, M_ / 256);   // (12, 32) = 384 blocks, 1/CU
    gemm8<<<gqkv, 512, 0, stream>>>(xf, wfq, bcat, qkvh);

    attn_local<<<M_ / 4, 256, 0, stream>>>(qkvh, ctxf);   // 2048 blocks

    dim3 go(C_ / 128, M_ / 256);             // (8, 32) = 256 blocks
    gemm_p2<0><<<go, 256, 0, stream>>>(ctxf, wfo, bo, out, C_);
}